// Round 1
// baseline (109.900 us; speedup 1.0000x reference)
//
#include <hip/hip_runtime.h>
#include <math.h>

// Problem constants (from reference)
#define N_ELEC   1024          // GRID 32x32, all valid
#define OUT_H    256
#define OUT_W    256
#define I_SCALE_C  8e-05f
#define RHEO_C     2.39e-05f
#define PW_C       0.00017f
#define FREQ_C     300.0f
#define SLOPE_C    19152642.5f
#define HALF_C     1.057e-07f
#define SPREAD_C   0.000675f
#define R2S_C      0.5f
#define LOG2E_C    1.4426950408889634f

__device__ __forceinline__ float fast_exp2(float x) {
#if __has_builtin(__builtin_amdgcn_exp2f)
    return __builtin_amdgcn_exp2f(x);
#else
    return exp2f(x);
#endif
}

// Per-(batch, electrode) parameter pack:
//   weighted gaussian = exp2( c*r2 + A*x + B*y + C )
// where x,y are pixel-space coords, r2 = x*x + y*y,
//   c = -log2(e)/(2*sigma_px^2)
//   A = -2*c*vx_px,  B = -2*c*vy_px
//   C = c*(vx_px^2 + vy_px^2) + log2(Bw)      (Bw = sigmoid(...) > 0 always)
__global__ __launch_bounds__(256) void param_kernel(
    const float* __restrict__ stim,   // [2, 1024]
    const float* __restrict__ vx,     // [1024]
    const float* __restrict__ vy,     // [1024]
    const float* __restrict__ M,      // [1024]
    const float* __restrict__ px,     // [256,256]; px[w] = xs[w], max at w=255
    const int*   __restrict__ idx,    // [1024]
    float4*      __restrict__ P,      // out: [2][1024]
    float*       __restrict__ scal)   // out: [0] = deg2pix
{
    int n = blockIdx.x * blockDim.x + threadIdx.x;
    if (n >= N_ELEC) return;

    float fov  = px[OUT_W - 1];                    // xs endpoint == px.max()
    float d2p  = (float)OUT_W / (2.0f * fov);      // deg2pix

    int   j    = idx[n];
    float vxp  = vx[n] * d2p;
    float vyp  = vy[n] * d2p;
    float invM = R2S_C / M[n];
    float v2   = vxp * vxp + vyp * vyp;

    for (int b = 0; b < 2; ++b) {
        float I    = stim[b * N_ELEC + j] * I_SCALE_C;
        float Ieff = fmaxf(I - RHEO_C, 0.0f);
        float Q    = Ieff * (PW_C * FREQ_C);
        float s    = SLOPE_C * (Q - HALF_C);       // |s| <= ~53, exp is safe
        float Bw   = 1.0f / (1.0f + __expf(-s));
        float size_base = sqrtf(I / SPREAD_C);
        float sigma_px  = fmaxf(size_base * invM * d2p, 1.0f);
        float c    = -LOG2E_C / (2.0f * sigma_px * sigma_px);
        float A    = -2.0f * c * vxp;
        float B    = -2.0f * c * vyp;
        float C    = c * v2 + log2f(Bw);
        P[b * N_ELEC + n] = make_float4(c, A, B, C);
    }
    if (n == 0) scal[0] = d2p;
}

__global__ __launch_bounds__(256) void render_kernel(
    const float*  __restrict__ px,
    const float*  __restrict__ py,
    const float4* __restrict__ P,     // [2][1024] packed params
    const float*  __restrict__ scal,  // [0] = deg2pix
    float*        __restrict__ out)   // [2,1,256,256]
{
    int w = threadIdx.x;              // 256 threads = one output row
    int h = blockIdx.x & (OUT_H - 1);
    int b = blockIdx.x >> 8;

    float d2p = scal[0];
    int pix = h * OUT_W + w;
    float x  = px[pix] * d2p;
    float y  = py[pix] * d2p;
    float r2 = x * x + y * y;

    const float4* Pb = P + b * N_ELEC;

    float a0 = 0.0f, a1 = 0.0f, a2 = 0.0f, a3 = 0.0f;
    // n is wave-uniform -> these become s_load_dwordx4 on the scalar pipe.
    for (int n = 0; n < N_ELEC; n += 4) {
        float4 p0 = Pb[n + 0];
        float4 p1 = Pb[n + 1];
        float4 p2 = Pb[n + 2];
        float4 p3 = Pb[n + 3];
        a0 += fast_exp2(fmaf(p0.x, r2, fmaf(p0.y, x, fmaf(p0.z, y, p0.w))));
        a1 += fast_exp2(fmaf(p1.x, r2, fmaf(p1.y, x, fmaf(p1.z, y, p1.w))));
        a2 += fast_exp2(fmaf(p2.x, r2, fmaf(p2.y, x, fmaf(p2.z, y, p2.w))));
        a3 += fast_exp2(fmaf(p3.x, r2, fmaf(p3.y, x, fmaf(p3.z, y, p3.w))));
    }
    float s = (a0 + a1) + (a2 + a3);
    out[b * (OUT_H * OUT_W) + pix] = fminf(fmaxf(s * 2.0f, 0.0f), 1.0f);
}

extern "C" void kernel_launch(void* const* d_in, const int* in_sizes, int n_in,
                              void* d_out, int out_size, void* d_ws, size_t ws_size,
                              hipStream_t stream) {
    const float* stim = (const float*)d_in[0];   // [2,32,32]
    const float* vx   = (const float*)d_in[1];   // [1024]
    const float* vy   = (const float*)d_in[2];   // [1024]
    const float* M    = (const float*)d_in[3];   // [1024]
    const float* px   = (const float*)d_in[4];   // [256,256]
    const float* py   = (const float*)d_in[5];   // [256,256]
    const int*   idx  = (const int*)d_in[6];     // [1024]
    float* out = (float*)d_out;

    float4* P    = (float4*)d_ws;                          // 2*1024 float4 = 32 KB
    float*  scal = (float*)((char*)d_ws + 2 * N_ELEC * sizeof(float4));

    param_kernel<<<(N_ELEC + 255) / 256, 256, 0, stream>>>(
        stim, vx, vy, M, px, idx, P, scal);
    render_kernel<<<2 * OUT_H, 256, 0, stream>>>(
        px, py, P, scal, out);
}

// Round 2
// 75.411 us; speedup vs baseline: 1.4573x; 1.4573x over previous
//
#include <hip/hip_runtime.h>
#include <math.h>

#define N_ELEC   1024
#define OUT_H    256
#define OUT_W    256
#define I_SCALE_C  8e-05f
#define RHEO_C     2.39e-05f
#define PW_C       0.00017f
#define FREQ_C     300.0f
#define SLOPE_C    19152642.5f
#define HALF_C     1.057e-07f
#define SPREAD_C   0.000675f
#define R2S_C      0.5f
#define LOG2E_C    1.4426950408889634f

typedef __attribute__((ext_vector_type(8))) short short8;
typedef __attribute__((ext_vector_type(4))) float float4v;

__device__ __forceinline__ float fast_exp2(float x) {
#if __has_builtin(__builtin_amdgcn_exp2f)
    return __builtin_amdgcn_exp2f(x);
#else
    return exp2f(x);
#endif
}

__device__ __forceinline__ unsigned short f2bf(float f) {
    unsigned int u = __float_as_uint(f);
    unsigned int r = (u + 0x7fffu + ((u >> 16) & 1u)) >> 16;
    return (unsigned short)r;
}

// Per-(b,n) params: (c, vx_px, vy_px, log2(Bw)); c = -log2e/(2*sigma_px^2)
__global__ __launch_bounds__(256) void param_kernel(
    const float* __restrict__ stim, const float* __restrict__ vx,
    const float* __restrict__ vy,   const float* __restrict__ M,
    const float* __restrict__ px,   const int* __restrict__ idx,
    float4* __restrict__ P)
{
    int n = blockIdx.x * blockDim.x + threadIdx.x;
    if (n >= N_ELEC) return;
    float fov  = px[OUT_W - 1];
    float d2p  = (float)OUT_W / (2.0f * fov);
    int   j    = idx[n];
    float vxp  = vx[n] * d2p;
    float vyp  = vy[n] * d2p;
    float invM = R2S_C / M[n];
    for (int b = 0; b < 2; ++b) {
        float I    = stim[b * N_ELEC + j] * I_SCALE_C;
        float Ieff = fmaxf(I - RHEO_C, 0.0f);
        float Q    = Ieff * (PW_C * FREQ_C);
        float s    = SLOPE_C * (Q - HALF_C);      // s in (-2.1, 55)
        float Bw   = 1.0f / (1.0f + __expf(-s));
        float size_base = sqrtf(I / SPREAD_C);
        float sigma_px  = fmaxf(size_base * invM * d2p, 1.0f);
        float c    = -LOG2E_C / (2.0f * sigma_px * sigma_px);
        P[b * N_ELEC + n] = make_float4(c, vxp, vyp, log2f(Bw));
    }
}

// Separable tables (bf16, k-innermost):
//   Ft[b][w][n] = exp2(c*(x_w - vx)^2)            in (0,1]
//   Gt[b][h][n] = exp2(c*(y_h - vy)^2 + log2Bw)   in (0,1]
__global__ __launch_bounds__(256) void table_kernel(
    const float4* __restrict__ P, const float* __restrict__ px,
    const float* __restrict__ py, unsigned short* __restrict__ Ft,
    unsigned short* __restrict__ Gt)
{
    int id   = blockIdx.x;          // 1024 blocks
    int b    = id >> 9;
    int half = (id >> 8) & 1;       // 0 = F (x), 1 = G (y)
    int p    = id & 255;            // w or h

    float fov = px[OUT_W - 1];
    float d2p = (float)OUT_W / (2.0f * fov);
    float coord = (half ? py[p * OUT_W] : px[p]) * d2p;   // block-uniform

    unsigned short* T = (half ? Gt : Ft) + ((size_t)(b * 256 + p)) * N_ELEC;
    const float4* Pb = P + b * N_ELEC;

    int n0 = threadIdx.x * 4;
    ushort4 v;
    {
        float4 q0 = Pb[n0 + 0];
        float4 q1 = Pb[n0 + 1];
        float4 q2 = Pb[n0 + 2];
        float4 q3 = Pb[n0 + 3];
        float d0 = coord - (half ? q0.z : q0.y);
        float d1 = coord - (half ? q1.z : q1.y);
        float d2 = coord - (half ? q2.z : q2.y);
        float d3 = coord - (half ? q3.z : q3.y);
        float e0 = fmaf(q0.x * d0, d0, half ? q0.w : 0.0f);
        float e1 = fmaf(q1.x * d1, d1, half ? q1.w : 0.0f);
        float e2 = fmaf(q2.x * d2, d2, half ? q2.w : 0.0f);
        float e3 = fmaf(q3.x * d3, d3, half ? q3.w : 0.0f);
        v.x = f2bf(fast_exp2(e0));
        v.y = f2bf(fast_exp2(e1));
        v.z = f2bf(fast_exp2(e2));
        v.w = f2bf(fast_exp2(e3));
    }
    *(ushort4*)(T + n0) = v;
}

// out[b][h][w] = clip(2 * sum_n Gt[b][h][n] * Ft[b][w][n], 0, 1)
// MFMA 16x16x32 bf16: A[m][k] = Gt[h0+m][k], B[k][n] = Ft[w0+n][k].
// 256 blocks x 4 waves; wave = (pair, khalf): 2 tiles/block, K split 2x512.
__global__ __launch_bounds__(256) void gemm_kernel(
    const unsigned short* __restrict__ Ft,
    const unsigned short* __restrict__ Gt,
    float* __restrict__ out)
{
    __shared__ float4v red[128];    // [pair][lane]

    int b     = blockIdx.x >> 7;
    int t     = blockIdx.x & 127;
    int wave  = threadIdx.x >> 6;
    int lane  = threadIdx.x & 63;
    int pair  = wave >> 1;
    int khalf = wave & 1;
    int tile  = t * 2 + pair;       // 0..255
    int h0    = (tile >> 4) * 16;
    int w0    = (tile & 15) * 16;
    int m     = lane & 15;
    int q     = lane >> 4;
    int kc0   = khalf * 512;

    const short8* pA = (const short8*)(Gt + ((size_t)(b * 256 + h0 + m)) * N_ELEC + kc0 + q * 8);
    const short8* pB = (const short8*)(Ft + ((size_t)(b * 256 + w0 + m)) * N_ELEC + kc0 + q * 8);

    float4v acc0 = {0.0f, 0.0f, 0.0f, 0.0f};
    float4v acc1 = {0.0f, 0.0f, 0.0f, 0.0f};
#pragma unroll
    for (int i = 0; i < 8; ++i) {
        short8 a0 = pA[i * 8];
        short8 b0 = pB[i * 8];
        short8 a1 = pA[i * 8 + 4];
        short8 b1 = pB[i * 8 + 4];
        acc0 = __builtin_amdgcn_mfma_f32_16x16x32_bf16(a0, b0, acc0, 0, 0, 0);
        acc1 = __builtin_amdgcn_mfma_f32_16x16x32_bf16(a1, b1, acc1, 0, 0, 0);
    }
    float4v acc = acc0 + acc1;

    if (khalf == 1) red[pair * 64 + lane] = acc;
    __syncthreads();
    if (khalf == 0) {
        float4v o = red[pair * 64 + lane];
        acc += o;
        float* dst = out + (size_t)b * (OUT_H * OUT_W) + (size_t)(h0 + q * 4) * OUT_W + w0 + m;
#pragma unroll
        for (int r = 0; r < 4; ++r) {
            float vv = fminf(fmaxf(acc[r] * 2.0f, 0.0f), 1.0f);
            dst[r * OUT_W] = vv;
        }
    }
}

extern "C" void kernel_launch(void* const* d_in, const int* in_sizes, int n_in,
                              void* d_out, int out_size, void* d_ws, size_t ws_size,
                              hipStream_t stream) {
    const float* stim = (const float*)d_in[0];
    const float* vx   = (const float*)d_in[1];
    const float* vy   = (const float*)d_in[2];
    const float* M    = (const float*)d_in[3];
    const float* px   = (const float*)d_in[4];
    const float* py   = (const float*)d_in[5];
    const int*   idx  = (const int*)d_in[6];
    float* out = (float*)d_out;

    char* ws = (char*)d_ws;
    float4* P = (float4*)ws;                                   // 32 KB
    unsigned short* Ft = (unsigned short*)(ws + 2 * N_ELEC * sizeof(float4));   // 1 MB
    unsigned short* Gt = Ft + (size_t)2 * 256 * N_ELEC;                         // 1 MB

    param_kernel<<<(N_ELEC + 255) / 256, 256, 0, stream>>>(stim, vx, vy, M, px, idx, P);
    table_kernel<<<1024, 256, 0, stream>>>(P, px, py, Ft, Gt);
    gemm_kernel<<<256, 256, 0, stream>>>(Ft, Gt, out);
}

// Round 3
// 70.814 us; speedup vs baseline: 1.5519x; 1.0649x over previous
//
#include <hip/hip_runtime.h>
#include <math.h>

#define N_ELEC   1024
#define OUT_H    256
#define OUT_W    256
#define I_SCALE_C  8e-05f
#define RHEO_C     2.39e-05f
#define PW_C       0.00017f
#define FREQ_C     300.0f
#define SLOPE_C    19152642.5f
#define HALF_C     1.057e-07f
#define SPREAD_C   0.000675f
#define R2S_C      0.5f
#define LOG2E_C    1.4426950408889634f

typedef __attribute__((ext_vector_type(8))) short short8;
typedef __attribute__((ext_vector_type(4))) float float4v;

__device__ __forceinline__ float fast_exp2(float x) {
#if __has_builtin(__builtin_amdgcn_exp2f)
    return __builtin_amdgcn_exp2f(x);
#else
    return exp2f(x);
#endif
}

__device__ __forceinline__ unsigned short f2bf(float f) {
    unsigned int u = __float_as_uint(f);
    unsigned int r = (u + 0x7fffu + ((u >> 16) & 1u)) >> 16;
    return (unsigned short)r;
}

// Fully fused: one block per (batch, 16x16 output tile). Each block
// recomputes the 1024 per-electrode params into LDS (cheap), then each of
// 4 waves MFMA-accumulates a K=256 electrode slice with register-resident
// bf16 fragments computed on the fly (separable Gaussian):
//   A[m][k] = exp2(c_k*(y_{h0+m}-vy_k)^2 + log2Bw_k)   (G factor, weighted)
//   B[k][n] = exp2(c_k*(x_{w0+n}-vx_k)^2)              (F factor)
// No global scratch, no inter-kernel syncs, d_ws untouched.
__global__ __launch_bounds__(256) void fused_kernel(
    const float* __restrict__ stim, const float* __restrict__ vx,
    const float* __restrict__ vy,   const float* __restrict__ M,
    const float* __restrict__ px,   const float* __restrict__ py,
    const int*   __restrict__ idx,  float* __restrict__ out)
{
    __shared__ float4  prm[N_ELEC];   // (c, vx_px, vy_px, log2Bw) per electrode
    __shared__ float4v red[192];      // waves 1..3 partial accumulators

    int b    = blockIdx.x >> 8;
    int tile = blockIdx.x & 255;
    int h0   = (tile >> 4) * 16;
    int w0   = (tile & 15) * 16;
    int tid  = threadIdx.x;
    int wave = tid >> 6;
    int lane = tid & 63;
    int m    = lane & 15;
    int q    = lane >> 4;

    float fov = px[OUT_W - 1];
    float d2p = (float)OUT_W / (2.0f * fov);

    // ---- phase 0: per-electrode params (coalesced; 4 per thread) ----
#pragma unroll
    for (int e = 0; e < 4; ++e) {
        int n = e * 256 + tid;
        int j = idx[n];
        float I    = stim[b * N_ELEC + j] * I_SCALE_C;
        float Ieff = fmaxf(I - RHEO_C, 0.0f);
        float Q    = Ieff * (PW_C * FREQ_C);
        float s    = SLOPE_C * (Q - HALF_C);        // s in (-2.1, ~55)
        float Bw   = 1.0f / (1.0f + __expf(-s));
        float size_base = sqrtf(I / SPREAD_C);
        float sigma_px  = fmaxf(size_base * (R2S_C / M[n]) * d2p, 1.0f);
        float c    = -LOG2E_C / (2.0f * sigma_px * sigma_px);
        prm[n] = make_float4(c, vx[n] * d2p, vy[n] * d2p, log2f(Bw));
    }
    __syncthreads();

    // ---- phase 1: register-fragment MFMA over this wave's K-slice ----
    float yv = py[(h0 + m) * OUT_W] * d2p;   // row coord for A fragment
    float xv = px[w0 + m] * d2p;             // col coord for B fragment
    int   k0 = wave * 256;

    float4v acc = {0.0f, 0.0f, 0.0f, 0.0f};
#pragma unroll
    for (int s = 0; s < 8; ++s) {
        int kb = k0 + s * 32 + q * 8;
        short8 af, bf;
#pragma unroll
        for (int j = 0; j < 8; ++j) {
            float4 p  = prm[kb + j];         // 16-lane broadcast, conflict-free
            float da  = yv - p.z;
            float ea  = fmaf(p.x * da, da, p.w);
            float db  = xv - p.y;
            float eb  = p.x * db * db;
            af[j] = (short)f2bf(fast_exp2(ea));
            bf[j] = (short)f2bf(fast_exp2(eb));
        }
        acc = __builtin_amdgcn_mfma_f32_16x16x32_bf16(af, bf, acc, 0, 0, 0);
    }

    // ---- phase 2: cross-wave K-reduce + store ----
    if (wave > 0) red[(wave - 1) * 64 + lane] = acc;
    __syncthreads();
    if (wave == 0) {
        acc += red[lane];
        acc += red[64 + lane];
        acc += red[128 + lane];
        float* dst = out + (size_t)b * (OUT_H * OUT_W)
                         + (size_t)(h0 + q * 4) * OUT_W + (w0 + m);
#pragma unroll
        for (int r = 0; r < 4; ++r)
            dst[r * OUT_W] = fminf(fmaxf(acc[r] * 2.0f, 0.0f), 1.0f);
    }
}

extern "C" void kernel_launch(void* const* d_in, const int* in_sizes, int n_in,
                              void* d_out, int out_size, void* d_ws, size_t ws_size,
                              hipStream_t stream) {
    const float* stim = (const float*)d_in[0];
    const float* vx   = (const float*)d_in[1];
    const float* vy   = (const float*)d_in[2];
    const float* M    = (const float*)d_in[3];
    const float* px   = (const float*)d_in[4];
    const float* py   = (const float*)d_in[5];
    const int*   idx  = (const int*)d_in[6];
    float* out = (float*)d_out;

    fused_kernel<<<512, 256, 0, stream>>>(stim, vx, vy, M, px, py, idx, out);
}